// Round 6
// baseline (338.394 us; speedup 1.0000x reference)
//
#include <hip/hip_runtime.h>
#include <hip/hip_bf16.h>
#include <math.h>

#define T_TRACKS 1024
#define HIDDEN 128
#define LATENT 16
#define NGRID 16
#define NCELLS 256
#define KDIM 4096
#define OUTD 128

typedef unsigned short ushort_t;
typedef __attribute__((ext_vector_type(8))) short frag_ab;   // 8 bf16
typedef __attribute__((ext_vector_type(4))) float f32x4;

static __device__ inline ushort_t f2bf(float x) {
    __hip_bfloat16 h = __float2bfloat16(x);
    return *reinterpret_cast<ushort_t*>(&h);
}

// ---------------- ws layout (byte offsets) ----------------
// vals_bf16 [1024][16]             @ 0          (32 KB)
// W_t bf16 [128 o][4096 k]         @ 32768      (1 MB)
// occ bf16 [1024][4096]            @ 1081344    (8 MB)
// partial f32 [32 kt][1024][128]   @ 9469952    (16 MB)
// flags int[32]                    @ 26247168   (grp[0..15], done[16..31])
#define WS_VALS 0
#define WS_WT   32768
#define WS_OCC  1081344
#define WS_PART 9469952
#define WS_FLAG 26247168
#define WS_NEED (26247168 + 256)

// ============ K1: prep (vals bf16 | W_emb transpose->bf16 | zero flags) ============
__global__ __launch_bounds__(256) void prep_kernel(const float* __restrict__ hidden,
                                                   const float* __restrict__ W_enc,
                                                   const float* __restrict__ b_enc,
                                                   const float* __restrict__ W_emb,
                                                   ushort_t* __restrict__ vals_bf16,
                                                   ushort_t* __restrict__ W_t,
                                                   int* __restrict__ flags) {
    const int b = blockIdx.x;
    const int tid = threadIdx.x;
    if (b < 64) {
        // vals[j][l] = hidden[j] @ W_enc[:,l] + b_enc[l]  -> bf16
        int idx = b * 256 + tid;           // 0..16383
        int j = idx >> 4, l = idx & 15;
        const float* h = hidden + j * HIDDEN;
        float acc = b_enc[l];
#pragma unroll 8
        for (int k = 0; k < HIDDEN; k++) acc += h[k] * W_enc[k * LATENT + l];
        vals_bf16[idx] = f2bf(acc);
    } else {
        // W_t[o][k] = bf16(W_emb[k][o]); thread handles (o, 8 consecutive k)
        int idx = (b - 64) * 256 + tid;    // 0..65535
        int kc = idx >> 7;                 // 0..511 (chunk of 8 k)
        int o = idx & 127;
        ushort_t tmp[8];
#pragma unroll
        for (int u = 0; u < 8; u++) tmp[u] = f2bf(W_emb[(kc * 8 + u) * OUTD + o]);
        *reinterpret_cast<uint4*>(W_t + o * KDIM + kc * 8) = *reinterpret_cast<uint4*>(tmp);
        if (b == 319 && tid < 32) flags[tid] = 0;   // zero sync words (ws is poisoned)
    }
}

// ============ K2: megakernel — occ (blocks 0..1023) + gemm/reduce (1024..1535) ============
// occ role: build track i's 4096-wide bf16 row (k = l*256 + c), then release grp[i>>6].
// gemm role (kt = g&31, mt = g>>5): spin-acquire grp[mt]==64, MFMA direct from
// global (no LDS), store partial slice, ACQ_REL done[mt]; last of 32 reduces
// + bias + relu -> out.  Deadlock-safe: launch_bounds(256,4) -> >=1024 resident
// blocks, only 512 ever wait, occ blocks never wait.
__global__ __launch_bounds__(256, 4) void mega_kernel(const float* __restrict__ obs2,
                                                      const ushort_t* __restrict__ vals_bf16,
                                                      const ushort_t* __restrict__ W_t,
                                                      ushort_t* __restrict__ occ,
                                                      float* __restrict__ partial,
                                                      int* __restrict__ flags,
                                                      const float* __restrict__ b_emb,
                                                      float* __restrict__ out) {
    const int bid = blockIdx.x;
    const int tid = threadIdx.x;

    __shared__ int owner[NCELLS];
    __shared__ ushort_t socc[LATENT * NCELLS];   // 8 KB
    __shared__ int bcast;

    if (bid < T_TRACKS) {
        // ---------------- occ role ----------------
        const int i = bid;
        owner[tid] = -1;
        float oix = obs2[i * 2 + 0];
        float oiy = obs2[i * 2 + 1];
        if (isnan(oix) || isnan(oiy)) { oix = 0.0f; oiy = 0.0f; }
        __syncthreads();

        for (int j = tid; j < T_TRACKS; j += 256) {
            if (j == i) continue;
            float ox = obs2[j * 2 + 0];
            float oy = obs2[j * 2 + 1];
            if (isnan(ox) || isnan(oy)) { ox = 0.0f; oy = 0.0f; }
            float gx = (ox - oix) * 0.5f + 8.0f;
            float gy = (oy - oiy) * 0.5f + 8.0f;
            bool inr = (gx >= 0.0f) && (gx < 16.0f) && (gy >= 0.0f) && (gy < 16.0f);
            int c = inr ? ((int)gx * NGRID + (int)gy) : 0;   // OOR scatters 0 into cell 0
            atomicMax(&owner[c], j);
        }
        __syncthreads();

        {
            const int c = tid;
            int j = owner[c];
            bool valid = (j >= 0);
            if (c == 0 && valid) {
                // cell 0's winner may be an out-of-range neighbor (value 0)
                float ox = obs2[j * 2 + 0];
                float oy = obs2[j * 2 + 1];
                if (isnan(ox) || isnan(oy)) { ox = 0.0f; oy = 0.0f; }
                float gx = (ox - oix) * 0.5f + 8.0f;
                float gy = (oy - oiy) * 0.5f + 8.0f;
                valid = (gx >= 0.0f) && (gx < 16.0f) && (gy >= 0.0f) && (gy < 16.0f);
            }
            int jj = (j >= 0) ? j : 0;
            ushort_t vv[16];
            *reinterpret_cast<uint4*>(vv)     = *reinterpret_cast<const uint4*>(vals_bf16 + jj * LATENT);
            *reinterpret_cast<uint4*>(vv + 8) = *reinterpret_cast<const uint4*>(vals_bf16 + jj * LATENT + 8);
#pragma unroll
            for (int l = 0; l < LATENT; l++) {
                socc[l * NCELLS + c] = valid ? vv[l] : (ushort_t)0;
            }
        }
        __syncthreads();

        uint4* dst = reinterpret_cast<uint4*>(occ + (size_t)i * KDIM);
        const uint4* src = reinterpret_cast<const uint4*>(socc);
        dst[tid]       = src[tid];
        dst[tid + 256] = src[tid + 256];

        __syncthreads();      // drain all threads' stores (vmcnt(0))
        __threadfence();      // agent-scope writeback
        if (tid == 0) {
            __hip_atomic_fetch_add(&flags[i >> 6], 1, __ATOMIC_RELEASE, __HIP_MEMORY_SCOPE_AGENT);
        }
        return;
    }

    // ---------------- gemm role ----------------
    const int g = bid - T_TRACKS;   // 0..511
    const int kt = g & 31;          // K segment (128 wide)
    const int mt = g >> 5;          // M stripe (64 rows)
    const int wave = tid >> 6;
    const int lane = tid & 63;
    const int lrow = lane & 15;
    const int quad = lane >> 4;

    // wait for this stripe's 64 occ rows
    if (tid == 0) {
        while (__hip_atomic_load(&flags[mt], __ATOMIC_ACQUIRE, __HIP_MEMORY_SCOPE_AGENT) < 64) {
            __builtin_amdgcn_s_sleep(8);
        }
        bcast = 1;
    }
    __syncthreads();
    __threadfence();   // acquire for all waves: invalidate stale L1/L2 lines

    const int k0 = kt * 128;
    f32x4 acc[8];
#pragma unroll
    for (int nt = 0; nt < 8; nt++) acc[nt] = (f32x4){0.f, 0.f, 0.f, 0.f};

    const ushort_t* arow = occ + (size_t)(mt * 64 + wave * 16 + lrow) * KDIM + k0 + quad * 8;
    const ushort_t* brow = W_t + (size_t)lrow * KDIM + k0 + quad * 8;
#pragma unroll
    for (int ks = 0; ks < 4; ks++) {   // K = 4 x 32 = 128
        frag_ab a = *reinterpret_cast<const frag_ab*>(arow + ks * 32);
#pragma unroll
        for (int nt = 0; nt < 8; nt++) {
            frag_ab bf = *reinterpret_cast<const frag_ab*>(brow + (size_t)nt * 16 * KDIM + ks * 32);
            acc[nt] = __builtin_amdgcn_mfma_f32_16x16x32_bf16(a, bf, acc[nt], 0, 0, 0);
        }
    }

    // store partial slice (C/D layout: col = lane&15, row = quad*4+reg)
    float* pt = partial + (size_t)kt * (T_TRACKS * OUTD) + (mt * 64) * OUTD;
#pragma unroll
    for (int nt = 0; nt < 8; nt++) {
        int n = nt * 16 + lrow;
#pragma unroll
        for (int reg = 0; reg < 4; reg++) {
            int m = wave * 16 + quad * 4 + reg;
            pt[m * OUTD + n] = acc[nt][reg];
        }
    }

    __syncthreads();      // drain partial stores
    __threadfence();      // writeback before signaling
    if (tid == 0) {
        int old = __hip_atomic_fetch_add(&flags[16 + mt], 1, __ATOMIC_ACQ_REL, __HIP_MEMORY_SCOPE_AGENT);
        bcast = (old == 31);
    }
    __syncthreads();
    if (!bcast) return;
    __threadfence();      // acquire: invalidate before reading other blocks' partials

    // last arriver: reduce 32 slices for this 64-row stripe + bias + relu
    const float4* p4 = reinterpret_cast<const float4*>(partial);
    const float4* b4 = reinterpret_cast<const float4*>(b_emb);
    float4* o4 = reinterpret_cast<float4*>(out);
    for (int idx = tid; idx < 2048; idx += 256) {   // 64 rows x 32 float4/row
        float4 s = p4[(size_t)mt * 2048 + idx];
#pragma unroll
        for (int k = 1; k < 32; k++) {
            float4 v = p4[(size_t)k * 32768 + mt * 2048 + idx];
            s.x += v.x; s.y += v.y; s.z += v.z; s.w += v.w;
        }
        float4 bv = b4[idx & 31];
        float4 r;
        r.x = fmaxf(s.x + bv.x, 0.0f);
        r.y = fmaxf(s.y + bv.y, 0.0f);
        r.z = fmaxf(s.z + bv.z, 0.0f);
        r.w = fmaxf(s.w + bv.w, 0.0f);
        o4[mt * 2048 + idx] = r;
    }
}

// ================= Round-1 fallback (f32, fused) for small ws =================
__global__ __launch_bounds__(256) void vals_kernel_f32(const float* __restrict__ hidden,
                                                       const float* __restrict__ W_enc,
                                                       const float* __restrict__ b_enc,
                                                       float* __restrict__ vals) {
    int idx = blockIdx.x * 256 + threadIdx.x;
    int j = idx >> 4, l = idx & 15;
    const float* h = hidden + j * HIDDEN;
    float acc = b_enc[l];
#pragma unroll 8
    for (int k = 0; k < HIDDEN; k++) acc += h[k] * W_enc[k * LATENT + l];
    vals[idx] = acc;
}

__global__ __launch_bounds__(256) void pool_kernel_f32(const float* __restrict__ obs2,
                                                       const float* __restrict__ vals,
                                                       const float* __restrict__ W_emb,
                                                       const float* __restrict__ b_emb,
                                                       float* __restrict__ out) {
    const int i = blockIdx.x;
    const int tid = threadIdx.x;
    __shared__ int owner[NCELLS];
    __shared__ float occ[NCELLS * LATENT];
    __shared__ float partial[OUTD];
    owner[tid] = -1;
    float oix = obs2[i * 2 + 0];
    float oiy = obs2[i * 2 + 1];
    if (isnan(oix) || isnan(oiy)) { oix = 0.0f; oiy = 0.0f; }
    __syncthreads();
    for (int j = tid; j < T_TRACKS; j += 256) {
        if (j == i) continue;
        float ox = obs2[j * 2 + 0], oy = obs2[j * 2 + 1];
        if (isnan(ox) || isnan(oy)) { ox = 0.0f; oy = 0.0f; }
        float gx = (ox - oix) * 0.5f + 8.0f;
        float gy = (oy - oiy) * 0.5f + 8.0f;
        bool inr = (gx >= 0.0f) && (gx < 16.0f) && (gy >= 0.0f) && (gy < 16.0f);
        int c = inr ? ((int)gx * NGRID + (int)gy) : 0;
        atomicMax(&owner[c], j);
    }
    __syncthreads();
    {
        int j = owner[tid];
        bool valid = false;
        if (j >= 0) {
            float ox = obs2[j * 2 + 0], oy = obs2[j * 2 + 1];
            if (isnan(ox) || isnan(oy)) { ox = 0.0f; oy = 0.0f; }
            float gx = (ox - oix) * 0.5f + 8.0f;
            float gy = (oy - oiy) * 0.5f + 8.0f;
            valid = (gx >= 0.0f) && (gx < 16.0f) && (gy >= 0.0f) && (gy < 16.0f);
        }
        const float* vj = vals + (j >= 0 ? j : 0) * LATENT;
#pragma unroll
        for (int l = 0; l < LATENT; l++) occ[tid * LATENT + l] = valid ? vj[l] : 0.0f;
    }
    __syncthreads();
    const int o = tid & (OUTD - 1);
    const int half = tid >> 7;
    const int cbase = half * 128;
    float acc = 0.0f;
    for (int c = cbase; c < cbase + 128; c++) {
#pragma unroll
        for (int l = 0; l < LATENT; l++)
            acc += occ[c * LATENT + l] * W_emb[(l * NCELLS + c) * OUTD + o];
    }
    if (half == 0) partial[o] = acc;
    __syncthreads();
    if (half == 1) out[i * OUTD + o] = fmaxf(acc + partial[o] + b_emb[o], 0.0f);
}

extern "C" void kernel_launch(void* const* d_in, const int* in_sizes, int n_in,
                              void* d_out, int out_size, void* d_ws, size_t ws_size,
                              hipStream_t stream) {
    const float* hidden = (const float*)d_in[0];   // [1024,128]
    const float* obs2   = (const float*)d_in[2];   // [1024,2]
    const float* W_enc  = (const float*)d_in[3];   // [128,16]
    const float* b_enc  = (const float*)d_in[4];   // [16]
    const float* W_emb  = (const float*)d_in[5];   // [4096,128]
    const float* b_emb  = (const float*)d_in[6];   // [128]
    float* out = (float*)d_out;                    // [1024,128]

    if (ws_size < (size_t)WS_NEED) {
        // fallback: round-1 verified f32 path
        float* vals = (float*)d_ws;
        vals_kernel_f32<<<(T_TRACKS * LATENT) / 256, 256, 0, stream>>>(hidden, W_enc, b_enc, vals);
        pool_kernel_f32<<<T_TRACKS, 256, 0, stream>>>(obs2, vals, W_emb, b_emb, out);
        return;
    }

    char* ws = (char*)d_ws;
    ushort_t* vals_bf16 = (ushort_t*)(ws + WS_VALS);
    ushort_t* W_t       = (ushort_t*)(ws + WS_WT);
    ushort_t* occ       = (ushort_t*)(ws + WS_OCC);
    float*    partial   = (float*)(ws + WS_PART);
    int*      flags     = (int*)(ws + WS_FLAG);

    prep_kernel<<<320, 256, 0, stream>>>(hidden, W_enc, b_enc, W_emb, vals_bf16, W_t, flags);
    mega_kernel<<<T_TRACKS + 512, 256, 0, stream>>>(obs2, vals_bf16, W_t, occ, partial,
                                                    flags, b_emb, out);
}

// Round 7
// 329.093 us; speedup vs baseline: 1.0283x; 1.0283x over previous
//
#include <hip/hip_runtime.h>
#include <hip/hip_bf16.h>
#include <math.h>

#define T_TRACKS 1024
#define HIDDEN 128
#define LATENT 16
#define NGRID 16
#define NCELLS 256
#define KDIM 4096
#define OUTD 128

typedef unsigned short ushort_t;
typedef __attribute__((ext_vector_type(8))) short frag_ab;   // 8 bf16
typedef __attribute__((ext_vector_type(4))) float f32x4;

static __device__ inline ushort_t f2bf(float x) {
    __hip_bfloat16 h = __float2bfloat16(x);
    return *reinterpret_cast<ushort_t*>(&h);
}

// ---------------- ws layout (byte offsets) ----------------
// vals_bf16 [1024][16]             @ 0          (32 KB)
// W_t bf16 [128 o][4096 k]         @ 32768      (1 MB)
// occ bf16 [1024][4096]            @ 1081344    (8 MB)
// partial f32 [32 kt][1024][128]   @ 9469952    (16 MB)
// flags int[32]                    @ 26247168   (grp[0..15], done[16..31])
#define WS_VALS 0
#define WS_WT   32768
#define WS_OCC  1081344
#define WS_PART 9469952
#define WS_FLAG 26247168
#define WS_NEED (26247168 + 256)

// ============ K1: prep (vals bf16 | W_emb transpose->bf16 | zero flags) ============
__global__ __launch_bounds__(256) void prep_kernel(const float* __restrict__ hidden,
                                                   const float* __restrict__ W_enc,
                                                   const float* __restrict__ b_enc,
                                                   const float* __restrict__ W_emb,
                                                   ushort_t* __restrict__ vals_bf16,
                                                   ushort_t* __restrict__ W_t,
                                                   int* __restrict__ flags) {
    const int b = blockIdx.x;
    const int tid = threadIdx.x;
    if (b < 64) {
        // vals[j][l] = hidden[j] @ W_enc[:,l] + b_enc[l]  -> bf16
        int idx = b * 256 + tid;           // 0..16383
        int j = idx >> 4, l = idx & 15;
        const float* h = hidden + j * HIDDEN;
        float acc = b_enc[l];
#pragma unroll 8
        for (int k = 0; k < HIDDEN; k++) acc += h[k] * W_enc[k * LATENT + l];
        vals_bf16[idx] = f2bf(acc);
    } else {
        // W_t[o][k] = bf16(W_emb[k][o]); thread handles (o, 8 consecutive k)
        int idx = (b - 64) * 256 + tid;    // 0..65535
        int kc = idx >> 7;                 // 0..511 (chunk of 8 k)
        int o = idx & 127;
        ushort_t tmp[8];
#pragma unroll
        for (int u = 0; u < 8; u++) tmp[u] = f2bf(W_emb[(kc * 8 + u) * OUTD + o]);
        *reinterpret_cast<uint4*>(W_t + o * KDIM + kc * 8) = *reinterpret_cast<uint4*>(tmp);
        if (b == 319 && tid < 32) flags[tid] = 0;   // zero sync words (ws is poisoned)
    }
}

// ============ K2: megakernel — occ (blocks 0..1023) + gemm/reduce (1024..1535) ============
// Roles alias one 52 KB LDS block -> 3 blocks/CU (LDS-capped) -> 768 resident
// slots > 512 total spinners -> deadlock-free for any dispatch order.
// NO min-waves bound: gemm role needs ~100 VGPRs; (256,4) caused scratch spills (R6).
#define LDSTR 136   // row stride in bf16 elems (128 + 8 pad)
#define SMEM_BYTES (192 * LDSTR * 2)   // As 64 rows + Bs 128 rows = 52224 B
__global__ __launch_bounds__(256) void mega_kernel(const float* __restrict__ obs2,
                                                   const ushort_t* __restrict__ vals_bf16,
                                                   const ushort_t* __restrict__ W_t,
                                                   ushort_t* __restrict__ occ,
                                                   float* __restrict__ partial,
                                                   int* __restrict__ flags,
                                                   const float* __restrict__ b_emb,
                                                   float* __restrict__ out) {
    const int bid = blockIdx.x;
    const int tid = threadIdx.x;

    __shared__ char smem[SMEM_BYTES];
    __shared__ int bcast;

    if (bid < T_TRACKS) {
        // ---------------- occ role ----------------
        int* owner = reinterpret_cast<int*>(smem);                     // 1 KB
        ushort_t* socc = reinterpret_cast<ushort_t*>(smem + 1024);     // 8 KB [l][c]
        const int i = bid;
        owner[tid] = -1;
        float oix = obs2[i * 2 + 0];
        float oiy = obs2[i * 2 + 1];
        if (isnan(oix) || isnan(oiy)) { oix = 0.0f; oiy = 0.0f; }
        __syncthreads();

        for (int j = tid; j < T_TRACKS; j += 256) {
            if (j == i) continue;
            float ox = obs2[j * 2 + 0];
            float oy = obs2[j * 2 + 1];
            if (isnan(ox) || isnan(oy)) { ox = 0.0f; oy = 0.0f; }
            float gx = (ox - oix) * 0.5f + 8.0f;
            float gy = (oy - oiy) * 0.5f + 8.0f;
            bool inr = (gx >= 0.0f) && (gx < 16.0f) && (gy >= 0.0f) && (gy < 16.0f);
            int c = inr ? ((int)gx * NGRID + (int)gy) : 0;   // OOR scatters 0 into cell 0
            atomicMax(&owner[c], j);
        }
        __syncthreads();

        {
            const int c = tid;
            int j = owner[c];
            bool valid = (j >= 0);
            if (c == 0 && valid) {
                // cell 0's winner may be an out-of-range neighbor (value 0)
                float ox = obs2[j * 2 + 0];
                float oy = obs2[j * 2 + 1];
                if (isnan(ox) || isnan(oy)) { ox = 0.0f; oy = 0.0f; }
                float gx = (ox - oix) * 0.5f + 8.0f;
                float gy = (oy - oiy) * 0.5f + 8.0f;
                valid = (gx >= 0.0f) && (gx < 16.0f) && (gy >= 0.0f) && (gy < 16.0f);
            }
            int jj = (j >= 0) ? j : 0;
            ushort_t vv[16];
            *reinterpret_cast<uint4*>(vv)     = *reinterpret_cast<const uint4*>(vals_bf16 + jj * LATENT);
            *reinterpret_cast<uint4*>(vv + 8) = *reinterpret_cast<const uint4*>(vals_bf16 + jj * LATENT + 8);
#pragma unroll
            for (int l = 0; l < LATENT; l++) {
                socc[l * NCELLS + c] = valid ? vv[l] : (ushort_t)0;
            }
        }
        __syncthreads();

        uint4* dst = reinterpret_cast<uint4*>(occ + (size_t)i * KDIM);
        const uint4* src = reinterpret_cast<const uint4*>(socc);
        dst[tid]       = src[tid];
        dst[tid + 256] = src[tid + 256];

        __syncthreads();      // drain all threads' stores
        __threadfence();      // agent-scope writeback
        if (tid == 0) {
            __hip_atomic_fetch_add(&flags[i >> 6], 1, __ATOMIC_RELEASE, __HIP_MEMORY_SCOPE_AGENT);
        }
        return;
    }

    // ---------------- gemm role ----------------
    const int g = bid - T_TRACKS;   // 0..511
    const int kt = g & 31;          // K segment (128 wide)
    const int mt = g >> 5;          // M stripe (64 rows)
    const int wave = tid >> 6;
    const int lane = tid & 63;
    const int lrow = lane & 15;
    const int quad = lane >> 4;

    ushort_t* As = reinterpret_cast<ushort_t*>(smem);            // 64 x LDSTR
    ushort_t* Bs = As + 64 * LDSTR;                              // 128 x LDSTR

    // wait for this stripe's 64 occ rows
    if (tid == 0) {
        while (__hip_atomic_load(&flags[mt], __ATOMIC_ACQUIRE, __HIP_MEMORY_SCOPE_AGENT) < 64) {
            __builtin_amdgcn_s_sleep(8);
        }
        bcast = 1;
    }
    __syncthreads();
    __threadfence();   // acquire for all waves

    const int k0 = kt * 128;
    f32x4 acc[8];
#pragma unroll
    for (int nt = 0; nt < 8; nt++) acc[nt] = (f32x4){0.f, 0.f, 0.f, 0.f};

    // stage A: 64 rows x 128 k = 1024 16B-granules (coalesced)
    for (int gg = tid; gg < 1024; gg += 256) {
        int r = gg >> 4, cs = gg & 15;
        uint4 v = *reinterpret_cast<const uint4*>(occ + (size_t)(mt * 64 + r) * KDIM + k0 + cs * 8);
        *reinterpret_cast<uint4*>(As + r * LDSTR + cs * 8) = v;
    }
    // stage B: 128 rows x 128 k = 2048 granules (coalesced)
    for (int gg = tid; gg < 2048; gg += 256) {
        int n = gg >> 4, cs = gg & 15;
        uint4 v = *reinterpret_cast<const uint4*>(W_t + (size_t)n * KDIM + k0 + cs * 8);
        *reinterpret_cast<uint4*>(Bs + n * LDSTR + cs * 8) = v;
    }
    __syncthreads();

#pragma unroll
    for (int ks = 0; ks < 4; ks++) {   // K = 4 x 32 = 128
        const int koff = ks * 32 + quad * 8;
        frag_ab a = *reinterpret_cast<const frag_ab*>(&As[(wave * 16 + lrow) * LDSTR + koff]);
#pragma unroll
        for (int nt = 0; nt < 8; nt++) {
            frag_ab bf = *reinterpret_cast<const frag_ab*>(&Bs[(nt * 16 + lrow) * LDSTR + koff]);
            acc[nt] = __builtin_amdgcn_mfma_f32_16x16x32_bf16(a, bf, acc[nt], 0, 0, 0);
        }
    }

    // store partial slice (C/D layout: col = lane&15, row = quad*4+reg)
    float* pt = partial + (size_t)kt * (T_TRACKS * OUTD) + (mt * 64) * OUTD;
#pragma unroll
    for (int nt = 0; nt < 8; nt++) {
        int n = nt * 16 + lrow;
#pragma unroll
        for (int reg = 0; reg < 4; reg++) {
            int m = wave * 16 + quad * 4 + reg;
            pt[m * OUTD + n] = acc[nt][reg];
        }
    }

    __syncthreads();      // drain partial stores
    __threadfence();      // writeback before signaling
    if (tid == 0) {
        int old = __hip_atomic_fetch_add(&flags[16 + mt], 1, __ATOMIC_ACQ_REL, __HIP_MEMORY_SCOPE_AGENT);
        bcast = ((old & 31) == 31);
    }
    __syncthreads();
    if (!bcast) return;
    __threadfence();      // acquire before reading other blocks' partials

    // last arriver: reduce 32 slices for this 64-row stripe + bias + relu
    const float4* p4 = reinterpret_cast<const float4*>(partial);
    const float4* b4 = reinterpret_cast<const float4*>(b_emb);
    float4* o4 = reinterpret_cast<float4*>(out);
    for (int idx = tid; idx < 2048; idx += 256) {   // 64 rows x 32 float4/row
        float4 s = p4[(size_t)mt * 2048 + idx];
#pragma unroll
        for (int k = 1; k < 32; k++) {
            float4 v = p4[(size_t)k * 32768 + mt * 2048 + idx];
            s.x += v.x; s.y += v.y; s.z += v.z; s.w += v.w;
        }
        float4 bv = b4[idx & 31];
        float4 r;
        r.x = fmaxf(s.x + bv.x, 0.0f);
        r.y = fmaxf(s.y + bv.y, 0.0f);
        r.z = fmaxf(s.z + bv.z, 0.0f);
        r.w = fmaxf(s.w + bv.w, 0.0f);
        o4[mt * 2048 + idx] = r;
    }
}

// ================= Round-1 fallback (f32, fused) for small ws =================
__global__ __launch_bounds__(256) void vals_kernel_f32(const float* __restrict__ hidden,
                                                       const float* __restrict__ W_enc,
                                                       const float* __restrict__ b_enc,
                                                       float* __restrict__ vals) {
    int idx = blockIdx.x * 256 + threadIdx.x;
    int j = idx >> 4, l = idx & 15;
    const float* h = hidden + j * HIDDEN;
    float acc = b_enc[l];
#pragma unroll 8
    for (int k = 0; k < HIDDEN; k++) acc += h[k] * W_enc[k * LATENT + l];
    vals[idx] = acc;
}

__global__ __launch_bounds__(256) void pool_kernel_f32(const float* __restrict__ obs2,
                                                       const float* __restrict__ vals,
                                                       const float* __restrict__ W_emb,
                                                       const float* __restrict__ b_emb,
                                                       float* __restrict__ out) {
    const int i = blockIdx.x;
    const int tid = threadIdx.x;
    __shared__ int owner[NCELLS];
    __shared__ float occ[NCELLS * LATENT];
    __shared__ float partial[OUTD];
    owner[tid] = -1;
    float oix = obs2[i * 2 + 0];
    float oiy = obs2[i * 2 + 1];
    if (isnan(oix) || isnan(oiy)) { oix = 0.0f; oiy = 0.0f; }
    __syncthreads();
    for (int j = tid; j < T_TRACKS; j += 256) {
        if (j == i) continue;
        float ox = obs2[j * 2 + 0], oy = obs2[j * 2 + 1];
        if (isnan(ox) || isnan(oy)) { ox = 0.0f; oy = 0.0f; }
        float gx = (ox - oix) * 0.5f + 8.0f;
        float gy = (oy - oiy) * 0.5f + 8.0f;
        bool inr = (gx >= 0.0f) && (gx < 16.0f) && (gy >= 0.0f) && (gy < 16.0f);
        int c = inr ? ((int)gx * NGRID + (int)gy) : 0;
        atomicMax(&owner[c], j);
    }
    __syncthreads();
    {
        int j = owner[tid];
        bool valid = false;
        if (j >= 0) {
            float ox = obs2[j * 2 + 0], oy = obs2[j * 2 + 1];
            if (isnan(ox) || isnan(oy)) { ox = 0.0f; oy = 0.0f; }
            float gx = (ox - oix) * 0.5f + 8.0f;
            float gy = (oy - oiy) * 0.5f + 8.0f;
            valid = (gx >= 0.0f) && (gx < 16.0f) && (gy >= 0.0f) && (gy < 16.0f);
        }
        const float* vj = vals + (j >= 0 ? j : 0) * LATENT;
#pragma unroll
        for (int l = 0; l < LATENT; l++) occ[tid * LATENT + l] = valid ? vj[l] : 0.0f;
    }
    __syncthreads();
    const int o = tid & (OUTD - 1);
    const int half = tid >> 7;
    const int cbase = half * 128;
    float acc = 0.0f;
    for (int c = cbase; c < cbase + 128; c++) {
#pragma unroll
        for (int l = 0; l < LATENT; l++)
            acc += occ[c * LATENT + l] * W_emb[(l * NCELLS + c) * OUTD + o];
    }
    if (half == 0) partial[o] = acc;
    __syncthreads();
    if (half == 1) out[i * OUTD + o] = fmaxf(acc + partial[o] + b_emb[o], 0.0f);
}

extern "C" void kernel_launch(void* const* d_in, const int* in_sizes, int n_in,
                              void* d_out, int out_size, void* d_ws, size_t ws_size,
                              hipStream_t stream) {
    const float* hidden = (const float*)d_in[0];   // [1024,128]
    const float* obs2   = (const float*)d_in[2];   // [1024,2]
    const float* W_enc  = (const float*)d_in[3];   // [128,16]
    const float* b_enc  = (const float*)d_in[4];   // [16]
    const float* W_emb  = (const float*)d_in[5];   // [4096,128]
    const float* b_emb  = (const float*)d_in[6];   // [128]
    float* out = (float*)d_out;                    // [1024,128]

    if (ws_size < (size_t)WS_NEED) {
        // fallback: round-1 verified f32 path
        float* vals = (float*)d_ws;
        vals_kernel_f32<<<(T_TRACKS * LATENT) / 256, 256, 0, stream>>>(hidden, W_enc, b_enc, vals);
        pool_kernel_f32<<<T_TRACKS, 256, 0, stream>>>(obs2, vals, W_emb, b_emb, out);
        return;
    }

    char* ws = (char*)d_ws;
    ushort_t* vals_bf16 = (ushort_t*)(ws + WS_VALS);
    ushort_t* W_t       = (ushort_t*)(ws + WS_WT);
    ushort_t* occ       = (ushort_t*)(ws + WS_OCC);
    float*    partial   = (float*)(ws + WS_PART);
    int*      flags     = (int*)(ws + WS_FLAG);

    prep_kernel<<<320, 256, 0, stream>>>(hidden, W_enc, b_enc, W_emb, vals_bf16, W_t, flags);
    mega_kernel<<<T_TRACKS + 512, 256, 0, stream>>>(obs2, vals_bf16, W_t, occ, partial,
                                                    flags, b_emb, out);
}

// Round 8
// 90.559 us; speedup vs baseline: 3.7367x; 3.6340x over previous
//
#include <hip/hip_runtime.h>
#include <hip/hip_bf16.h>
#include <math.h>

#define T_TRACKS 1024
#define HIDDEN 128
#define LATENT 16
#define NGRID 16
#define NCELLS 256
#define KDIM 4096
#define OUTD 128

typedef unsigned short ushort_t;
typedef __attribute__((ext_vector_type(8))) short frag_ab;   // 8 bf16
typedef __attribute__((ext_vector_type(4))) float f32x4;

static __device__ inline ushort_t f2bf(float x) {
    __hip_bfloat16 h = __float2bfloat16(x);
    return *reinterpret_cast<ushort_t*>(&h);
}

// ---------------- ws layout (byte offsets) ----------------
// vals_bf16 [1024][16]             @ 0         (32 KB)
// W_t bf16 [128 o][4096 k]         @ 32768     (1 MB)
// occ bf16 [1024][4096]            @ 1081344   (8 MB)
// partial f32 [16 kt][1024][128]   @ 9469952   (8 MB)
#define WS_VALS 0
#define WS_WT   32768
#define WS_OCC  1081344
#define WS_PART 9469952
#define WS_NEED (9469952 + 8388608)

// ============ K1: prep (vals bf16 | W_emb transpose->bf16) ============
__global__ __launch_bounds__(256) void prep_kernel(const float* __restrict__ hidden,
                                                   const float* __restrict__ W_enc,
                                                   const float* __restrict__ b_enc,
                                                   const float* __restrict__ W_emb,
                                                   ushort_t* __restrict__ vals_bf16,
                                                   ushort_t* __restrict__ W_t) {
    const int b = blockIdx.x;
    const int tid = threadIdx.x;
    if (b < 64) {
        // vals[j][l] = hidden[j] @ W_enc[:,l] + b_enc[l]  -> bf16
        int idx = b * 256 + tid;           // 0..16383
        int j = idx >> 4, l = idx & 15;
        const float* h = hidden + j * HIDDEN;
        float acc = b_enc[l];
#pragma unroll 8
        for (int k = 0; k < HIDDEN; k++) acc += h[k] * W_enc[k * LATENT + l];
        vals_bf16[idx] = f2bf(acc);
    } else {
        // W_t[o][k] = bf16(W_emb[k][o]); thread handles (o, 8 consecutive k)
        int idx = (b - 64) * 256 + tid;    // 0..65535
        int kc = idx >> 7;                 // 0..511 (chunk of 8 k)
        int o = idx & 127;
        ushort_t tmp[8];
#pragma unroll
        for (int u = 0; u < 8; u++) tmp[u] = f2bf(W_emb[(kc * 8 + u) * OUTD + o]);
        *reinterpret_cast<uint4*>(W_t + o * KDIM + kc * 8) = *reinterpret_cast<uint4*>(tmp);
    }
}

// ============ K2: build occ rows (bf16, k = l*256 + c order) ============
// Thread t == cell c: winner's 16 latents read as one contiguous 32B load,
// transposed through LDS, then 8KB row stored coalesced.
__global__ __launch_bounds__(256) void occ_kernel(const float* __restrict__ obs2,
                                                  const ushort_t* __restrict__ vals_bf16,
                                                  ushort_t* __restrict__ occ) {
    const int i = blockIdx.x;
    const int tid = threadIdx.x;
    __shared__ int owner[NCELLS];
    __shared__ ushort_t socc[LATENT * NCELLS];   // [l][c], 8 KB
    owner[tid] = -1;

    const float2* o2 = reinterpret_cast<const float2*>(obs2);
    float2 oi = o2[i];
    if (isnan(oi.x) || isnan(oi.y)) { oi.x = 0.0f; oi.y = 0.0f; }
    __syncthreads();

    for (int j = tid; j < T_TRACKS; j += 256) {
        if (j == i) continue;
        float2 oj = o2[j];
        if (isnan(oj.x) || isnan(oj.y)) { oj.x = 0.0f; oj.y = 0.0f; }
        float gx = (oj.x - oi.x) * 0.5f + 8.0f;
        float gy = (oj.y - oi.y) * 0.5f + 8.0f;
        bool inr = (gx >= 0.0f) && (gx < 16.0f) && (gy >= 0.0f) && (gy < 16.0f);
        int c = inr ? ((int)gx * NGRID + (int)gy) : 0;   // OOR scatters 0 into cell 0
        atomicMax(&owner[c], j);
    }
    __syncthreads();

    {
        const int c = tid;
        int j = owner[c];
        bool valid = (j >= 0);
        if (c == 0 && valid) {
            // cell 0's winner may be an out-of-range neighbor (value 0)
            float2 oj = o2[j];
            if (isnan(oj.x) || isnan(oj.y)) { oj.x = 0.0f; oj.y = 0.0f; }
            float gx = (oj.x - oi.x) * 0.5f + 8.0f;
            float gy = (oj.y - oi.y) * 0.5f + 8.0f;
            valid = (gx >= 0.0f) && (gx < 16.0f) && (gy >= 0.0f) && (gy < 16.0f);
        }
        int jj = (j >= 0) ? j : 0;
        ushort_t vv[16];
        *reinterpret_cast<uint4*>(vv)     = *reinterpret_cast<const uint4*>(vals_bf16 + jj * LATENT);
        *reinterpret_cast<uint4*>(vv + 8) = *reinterpret_cast<const uint4*>(vals_bf16 + jj * LATENT + 8);
#pragma unroll
        for (int l = 0; l < LATENT; l++) {
            socc[l * NCELLS + c] = valid ? vv[l] : (ushort_t)0;
        }
    }
    __syncthreads();

    // coalesced store of the 4096-elem row (512 uint4, 2 per thread)
    uint4* dst = reinterpret_cast<uint4*>(occ + (size_t)i * KDIM);
    const uint4* src = reinterpret_cast<const uint4*>(socc);
    dst[tid]       = src[tid];
    dst[tid + 256] = src[tid + 256];
}

// ============ K3: MFMA GEMM, K-split partials (no atomics, no cross-block sync) ============
// grid = 256: kt = blockIdx & 15 (Kseg=256), mt = blockIdx >> 4 (Mtile=64)
#define BK 128
#define LDSTR 136   // row stride in bf16 elems (128 + 8 pad)
__global__ __launch_bounds__(256) void gemm_kernel(const ushort_t* __restrict__ occ,
                                                   const ushort_t* __restrict__ W_t,
                                                   float* __restrict__ partial) {
    const int tid = threadIdx.x;
    const int kt = blockIdx.x & 15;
    const int mt = blockIdx.x >> 4;
    const int wave = tid >> 6;
    const int lane = tid & 63;
    const int lrow = lane & 15;
    const int quad = lane >> 4;

    __shared__ ushort_t As[64 * LDSTR];    // 17408 B
    __shared__ ushort_t Bs[128 * LDSTR];   // 34816 B

    f32x4 acc[8];
#pragma unroll
    for (int nt = 0; nt < 8; nt++) acc[nt] = (f32x4){0.f, 0.f, 0.f, 0.f};

    for (int chunk = 0; chunk < 2; chunk++) {
        const int k0 = kt * 256 + chunk * BK;
        // stage A: 64 rows x 128 k = 1024 16B-granules
        for (int g = tid; g < 1024; g += 256) {
            int r = g >> 4, cs = g & 15;
            uint4 v = *reinterpret_cast<const uint4*>(occ + (size_t)(mt * 64 + r) * KDIM + k0 + cs * 8);
            *reinterpret_cast<uint4*>(As + r * LDSTR + cs * 8) = v;
        }
        // stage B: 128 rows x 128 k = 2048 granules
        for (int g = tid; g < 2048; g += 256) {
            int n = g >> 4, cs = g & 15;
            uint4 v = *reinterpret_cast<const uint4*>(W_t + (size_t)n * KDIM + k0 + cs * 8);
            *reinterpret_cast<uint4*>(Bs + n * LDSTR + cs * 8) = v;
        }
        __syncthreads();
#pragma unroll
        for (int ks = 0; ks < 4; ks++) {   // K=32 per mfma
            const int koff = ks * 32 + quad * 8;
            frag_ab a = *reinterpret_cast<const frag_ab*>(&As[(wave * 16 + lrow) * LDSTR + koff]);
#pragma unroll
            for (int nt = 0; nt < 8; nt++) {
                frag_ab bfr = *reinterpret_cast<const frag_ab*>(&Bs[(nt * 16 + lrow) * LDSTR + koff]);
                acc[nt] = __builtin_amdgcn_mfma_f32_16x16x32_bf16(a, bfr, acc[nt], 0, 0, 0);
            }
        }
        __syncthreads();
    }
    // C/D layout: col = lane&15, row = quad*4+reg (m89/m91-verified).
    // Plain coalesced stores into this block's private partial tile.
    float* pt = partial + (size_t)kt * (T_TRACKS * OUTD) + (mt * 64) * OUTD;
#pragma unroll
    for (int nt = 0; nt < 8; nt++) {
        int n = nt * 16 + lrow;
#pragma unroll
        for (int reg = 0; reg < 4; reg++) {
            int m = wave * 16 + quad * 4 + reg;
            pt[m * OUTD + n] = acc[nt][reg];
        }
    }
}

// ============ K4: reduce 16 partials + bias + relu ============
__global__ __launch_bounds__(256) void reduce_kernel(const float* __restrict__ partial,
                                                     const float* __restrict__ b_emb,
                                                     float* __restrict__ out) {
    int idx = blockIdx.x * 256 + threadIdx.x;   // 0..32767 (float4 groups of [1024][128])
    const float4* p4 = reinterpret_cast<const float4*>(partial);
    float4 s = p4[idx];
#pragma unroll
    for (int kt = 1; kt < 16; kt++) {
        float4 v = p4[kt * 32768 + idx];
        s.x += v.x; s.y += v.y; s.z += v.z; s.w += v.w;
    }
    float4 bv = reinterpret_cast<const float4*>(b_emb)[idx & 31];
    float4 r;
    r.x = fmaxf(s.x + bv.x, 0.0f);
    r.y = fmaxf(s.y + bv.y, 0.0f);
    r.z = fmaxf(s.z + bv.z, 0.0f);
    r.w = fmaxf(s.w + bv.w, 0.0f);
    reinterpret_cast<float4*>(out)[idx] = r;
}

// ================= Round-1 fallback (f32, fused) for small ws =================
__global__ __launch_bounds__(256) void vals_kernel_f32(const float* __restrict__ hidden,
                                                       const float* __restrict__ W_enc,
                                                       const float* __restrict__ b_enc,
                                                       float* __restrict__ vals) {
    int idx = blockIdx.x * 256 + threadIdx.x;
    int j = idx >> 4, l = idx & 15;
    const float* h = hidden + j * HIDDEN;
    float acc = b_enc[l];
#pragma unroll 8
    for (int k = 0; k < HIDDEN; k++) acc += h[k] * W_enc[k * LATENT + l];
    vals[idx] = acc;
}

__global__ __launch_bounds__(256) void pool_kernel_f32(const float* __restrict__ obs2,
                                                       const float* __restrict__ vals,
                                                       const float* __restrict__ W_emb,
                                                       const float* __restrict__ b_emb,
                                                       float* __restrict__ out) {
    const int i = blockIdx.x;
    const int tid = threadIdx.x;
    __shared__ int owner[NCELLS];
    __shared__ float occ[NCELLS * LATENT];
    __shared__ float partial[OUTD];
    owner[tid] = -1;
    float oix = obs2[i * 2 + 0];
    float oiy = obs2[i * 2 + 1];
    if (isnan(oix) || isnan(oiy)) { oix = 0.0f; oiy = 0.0f; }
    __syncthreads();
    for (int j = tid; j < T_TRACKS; j += 256) {
        if (j == i) continue;
        float ox = obs2[j * 2 + 0], oy = obs2[j * 2 + 1];
        if (isnan(ox) || isnan(oy)) { ox = 0.0f; oy = 0.0f; }
        float gx = (ox - oix) * 0.5f + 8.0f;
        float gy = (oy - oiy) * 0.5f + 8.0f;
        bool inr = (gx >= 0.0f) && (gx < 16.0f) && (gy >= 0.0f) && (gy < 16.0f);
        int c = inr ? ((int)gx * NGRID + (int)gy) : 0;
        atomicMax(&owner[c], j);
    }
    __syncthreads();
    {
        int j = owner[tid];
        bool valid = false;
        if (j >= 0) {
            float ox = obs2[j * 2 + 0], oy = obs2[j * 2 + 1];
            if (isnan(ox) || isnan(oy)) { ox = 0.0f; oy = 0.0f; }
            float gx = (ox - oix) * 0.5f + 8.0f;
            float gy = (oy - oiy) * 0.5f + 8.0f;
            valid = (gx >= 0.0f) && (gx < 16.0f) && (gy >= 0.0f) && (gy < 16.0f);
        }
        const float* vj = vals + (j >= 0 ? j : 0) * LATENT;
#pragma unroll
        for (int l = 0; l < LATENT; l++) occ[tid * LATENT + l] = valid ? vj[l] : 0.0f;
    }
    __syncthreads();
    const int o = tid & (OUTD - 1);
    const int half = tid >> 7;
    const int cbase = half * 128;
    float acc = 0.0f;
    for (int c = cbase; c < cbase + 128; c++) {
#pragma unroll
        for (int l = 0; l < LATENT; l++)
            acc += occ[c * LATENT + l] * W_emb[(l * NCELLS + c) * OUTD + o];
    }
    if (half == 0) partial[o] = acc;
    __syncthreads();
    if (half == 1) out[i * OUTD + o] = fmaxf(acc + partial[o] + b_emb[o], 0.0f);
}

extern "C" void kernel_launch(void* const* d_in, const int* in_sizes, int n_in,
                              void* d_out, int out_size, void* d_ws, size_t ws_size,
                              hipStream_t stream) {
    const float* hidden = (const float*)d_in[0];   // [1024,128]
    const float* obs2   = (const float*)d_in[2];   // [1024,2]
    const float* W_enc  = (const float*)d_in[3];   // [128,16]
    const float* b_enc  = (const float*)d_in[4];   // [16]
    const float* W_emb  = (const float*)d_in[5];   // [4096,128]
    const float* b_emb  = (const float*)d_in[6];   // [128]
    float* out = (float*)d_out;                    // [1024,128]

    if (ws_size < (size_t)WS_NEED) {
        // fallback: round-1 verified f32 path
        float* vals = (float*)d_ws;
        vals_kernel_f32<<<(T_TRACKS * LATENT) / 256, 256, 0, stream>>>(hidden, W_enc, b_enc, vals);
        pool_kernel_f32<<<T_TRACKS, 256, 0, stream>>>(obs2, vals, W_emb, b_emb, out);
        return;
    }

    char* ws = (char*)d_ws;
    ushort_t* vals_bf16 = (ushort_t*)(ws + WS_VALS);
    ushort_t* W_t       = (ushort_t*)(ws + WS_WT);
    ushort_t* occ       = (ushort_t*)(ws + WS_OCC);
    float*    partial   = (float*)(ws + WS_PART);

    prep_kernel<<<320, 256, 0, stream>>>(hidden, W_enc, b_enc, W_emb, vals_bf16, W_t);
    occ_kernel<<<T_TRACKS, 256, 0, stream>>>(obs2, vals_bf16, occ);
    gemm_kernel<<<256, 256, 0, stream>>>(occ, W_t, partial);
    reduce_kernel<<<128, 256, 0, stream>>>(partial, b_emb, out);
}

// Round 9
// 90.555 us; speedup vs baseline: 3.7369x; 1.0000x over previous
//
#include <hip/hip_runtime.h>
#include <hip/hip_bf16.h>
#include <math.h>

#define T_TRACKS 1024
#define HIDDEN 128
#define LATENT 16
#define NGRID 16
#define NCELLS 256
#define KDIM 4096
#define OUTD 128

typedef unsigned short ushort_t;
typedef __attribute__((ext_vector_type(8))) short frag_ab;   // 8 bf16
typedef __attribute__((ext_vector_type(4))) float f32x4;

static __device__ inline ushort_t f2bf(float x) {
    __hip_bfloat16 h = __float2bfloat16(x);
    return *reinterpret_cast<ushort_t*>(&h);
}

// ---------------- ws layout (byte offsets) ----------------
// vals_bf16 [1024][16]             @ 0         (32 KB)
// W_t bf16 [128 o][4096 k]         @ 32768     (1 MB)
// occ bf16 [1024][4096]            @ 1081344   (8 MB)
// partial f32 [16 kt][1024][128]   @ 9469952   (8 MB)
#define WS_VALS 0
#define WS_WT   32768
#define WS_OCC  1081344
#define WS_PART 9469952
#define WS_NEED (9469952 + 8388608)

// ============ K1: prep (vals bf16 | W_emb transpose->bf16) ============
__global__ __launch_bounds__(256) void prep_kernel(const float* __restrict__ hidden,
                                                   const float* __restrict__ W_enc,
                                                   const float* __restrict__ b_enc,
                                                   const float* __restrict__ W_emb,
                                                   ushort_t* __restrict__ vals_bf16,
                                                   ushort_t* __restrict__ W_t) {
    const int b = blockIdx.x;
    const int tid = threadIdx.x;
    if (b < 64) {
        // vals[j][l] = hidden[j] @ W_enc[:,l] + b_enc[l]  -> bf16
        int idx = b * 256 + tid;           // 0..16383
        int j = idx >> 4, l = idx & 15;
        const float* h = hidden + j * HIDDEN;
        float acc = b_enc[l];
#pragma unroll 8
        for (int k = 0; k < HIDDEN; k++) acc += h[k] * W_enc[k * LATENT + l];
        vals_bf16[idx] = f2bf(acc);
    } else {
        // W_t[o][k] = bf16(W_emb[k][o]); thread handles (o, 8 consecutive k)
        // NO local-array punning: pack pairs into named registers.
        int idx = (b - 64) * 256 + tid;    // 0..65535
        int kc = idx >> 7;                 // 0..511 (chunk of 8 k)
        int o = idx & 127;
        const float* src = W_emb + (size_t)(kc * 8) * OUTD + o;
        unsigned p0 = (unsigned)f2bf(src[0 * OUTD]) | ((unsigned)f2bf(src[1 * OUTD]) << 16);
        unsigned p1 = (unsigned)f2bf(src[2 * OUTD]) | ((unsigned)f2bf(src[3 * OUTD]) << 16);
        unsigned p2 = (unsigned)f2bf(src[4 * OUTD]) | ((unsigned)f2bf(src[5 * OUTD]) << 16);
        unsigned p3 = (unsigned)f2bf(src[6 * OUTD]) | ((unsigned)f2bf(src[7 * OUTD]) << 16);
        uint4 pv; pv.x = p0; pv.y = p1; pv.z = p2; pv.w = p3;
        *reinterpret_cast<uint4*>(W_t + (size_t)o * KDIM + kc * 8) = pv;
    }
}

// ============ K2: build occ rows (bf16, k = l*256 + c order) ============
// Thread t == cell c: winner's 16 latents read as two uint4 into NAMED
// registers (no local-array punning / scratch), shift-extracted into the
// LDS transpose buffer, then 8KB row stored coalesced.
__global__ __launch_bounds__(256) void occ_kernel(const float* __restrict__ obs2,
                                                  const ushort_t* __restrict__ vals_bf16,
                                                  ushort_t* __restrict__ occ) {
    const int i = blockIdx.x;
    const int tid = threadIdx.x;
    __shared__ int owner[NCELLS];
    __shared__ ushort_t socc[LATENT * NCELLS];   // [l][c], 8 KB
    owner[tid] = -1;

    const float2* o2 = reinterpret_cast<const float2*>(obs2);
    float2 oi = o2[i];
    if (isnan(oi.x) || isnan(oi.y)) { oi.x = 0.0f; oi.y = 0.0f; }
    __syncthreads();

    for (int j = tid; j < T_TRACKS; j += 256) {
        if (j == i) continue;
        float2 oj = o2[j];
        if (isnan(oj.x) || isnan(oj.y)) { oj.x = 0.0f; oj.y = 0.0f; }
        float gx = (oj.x - oi.x) * 0.5f + 8.0f;
        float gy = (oj.y - oi.y) * 0.5f + 8.0f;
        bool inr = (gx >= 0.0f) && (gx < 16.0f) && (gy >= 0.0f) && (gy < 16.0f);
        int c = inr ? ((int)gx * NGRID + (int)gy) : 0;   // OOR scatters 0 into cell 0
        atomicMax(&owner[c], j);
    }
    __syncthreads();

    {
        const int c = tid;
        int j = owner[c];
        bool valid = (j >= 0);
        if (c == 0 && valid) {
            // cell 0's winner may be an out-of-range neighbor (value 0)
            float2 oj = o2[j];
            if (isnan(oj.x) || isnan(oj.y)) { oj.x = 0.0f; oj.y = 0.0f; }
            float gx = (oj.x - oi.x) * 0.5f + 8.0f;
            float gy = (oj.y - oi.y) * 0.5f + 8.0f;
            valid = (gx >= 0.0f) && (gx < 16.0f) && (gy >= 0.0f) && (gy < 16.0f);
        }
        int jj = (j >= 0) ? j : 0;
        const uint4* vsrc = reinterpret_cast<const uint4*>(vals_bf16);  // 2 uint4 per 16-latent row
        uint4 lo = vsrc[jj * 2];
        uint4 hi = vsrc[jj * 2 + 1];
        if (!valid) {
            lo.x = lo.y = lo.z = lo.w = 0u;
            hi.x = hi.y = hi.z = hi.w = 0u;
        }
        socc[ 0 * NCELLS + c] = (ushort_t)(lo.x & 0xffffu);
        socc[ 1 * NCELLS + c] = (ushort_t)(lo.x >> 16);
        socc[ 2 * NCELLS + c] = (ushort_t)(lo.y & 0xffffu);
        socc[ 3 * NCELLS + c] = (ushort_t)(lo.y >> 16);
        socc[ 4 * NCELLS + c] = (ushort_t)(lo.z & 0xffffu);
        socc[ 5 * NCELLS + c] = (ushort_t)(lo.z >> 16);
        socc[ 6 * NCELLS + c] = (ushort_t)(lo.w & 0xffffu);
        socc[ 7 * NCELLS + c] = (ushort_t)(lo.w >> 16);
        socc[ 8 * NCELLS + c] = (ushort_t)(hi.x & 0xffffu);
        socc[ 9 * NCELLS + c] = (ushort_t)(hi.x >> 16);
        socc[10 * NCELLS + c] = (ushort_t)(hi.y & 0xffffu);
        socc[11 * NCELLS + c] = (ushort_t)(hi.y >> 16);
        socc[12 * NCELLS + c] = (ushort_t)(hi.z & 0xffffu);
        socc[13 * NCELLS + c] = (ushort_t)(hi.z >> 16);
        socc[14 * NCELLS + c] = (ushort_t)(hi.w & 0xffffu);
        socc[15 * NCELLS + c] = (ushort_t)(hi.w >> 16);
    }
    __syncthreads();

    // coalesced store of the 4096-elem row (512 uint4, 2 per thread; LDS src)
    uint4* dst = reinterpret_cast<uint4*>(occ + (size_t)i * KDIM);
    const uint4* src = reinterpret_cast<const uint4*>(socc);
    dst[tid]       = src[tid];
    dst[tid + 256] = src[tid + 256];
}

// ============ K3: MFMA GEMM, K-split partials (no atomics, no cross-block sync) ============
// grid = 256: kt = blockIdx & 15 (Kseg=256), mt = blockIdx >> 4 (Mtile=64)
#define BK 128
#define LDSTR 136   // row stride in bf16 elems (128 + 8 pad)
__global__ __launch_bounds__(256) void gemm_kernel(const ushort_t* __restrict__ occ,
                                                   const ushort_t* __restrict__ W_t,
                                                   float* __restrict__ partial) {
    const int tid = threadIdx.x;
    const int kt = blockIdx.x & 15;
    const int mt = blockIdx.x >> 4;
    const int wave = tid >> 6;
    const int lane = tid & 63;
    const int lrow = lane & 15;
    const int quad = lane >> 4;

    __shared__ ushort_t As[64 * LDSTR];    // 17408 B
    __shared__ ushort_t Bs[128 * LDSTR];   // 34816 B

    f32x4 acc[8];
#pragma unroll
    for (int nt = 0; nt < 8; nt++) acc[nt] = (f32x4){0.f, 0.f, 0.f, 0.f};

    for (int chunk = 0; chunk < 2; chunk++) {
        const int k0 = kt * 256 + chunk * BK;
        // stage A: 64 rows x 128 k = 1024 16B-granules
        for (int g = tid; g < 1024; g += 256) {
            int r = g >> 4, cs = g & 15;
            uint4 v = *reinterpret_cast<const uint4*>(occ + (size_t)(mt * 64 + r) * KDIM + k0 + cs * 8);
            *reinterpret_cast<uint4*>(As + r * LDSTR + cs * 8) = v;
        }
        // stage B: 128 rows x 128 k = 2048 granules
        for (int g = tid; g < 2048; g += 256) {
            int n = g >> 4, cs = g & 15;
            uint4 v = *reinterpret_cast<const uint4*>(W_t + (size_t)n * KDIM + k0 + cs * 8);
            *reinterpret_cast<uint4*>(Bs + n * LDSTR + cs * 8) = v;
        }
        __syncthreads();
#pragma unroll
        for (int ks = 0; ks < 4; ks++) {   // K=32 per mfma
            const int koff = ks * 32 + quad * 8;
            frag_ab a = *reinterpret_cast<const frag_ab*>(&As[(wave * 16 + lrow) * LDSTR + koff]);
#pragma unroll
            for (int nt = 0; nt < 8; nt++) {
                frag_ab bfr = *reinterpret_cast<const frag_ab*>(&Bs[(nt * 16 + lrow) * LDSTR + koff]);
                acc[nt] = __builtin_amdgcn_mfma_f32_16x16x32_bf16(a, bfr, acc[nt], 0, 0, 0);
            }
        }
        __syncthreads();
    }
    // C/D layout: col = lane&15, row = quad*4+reg (m89/m91-verified).
    // Plain coalesced stores into this block's private partial tile.
    float* pt = partial + (size_t)kt * (T_TRACKS * OUTD) + (mt * 64) * OUTD;
#pragma unroll
    for (int nt = 0; nt < 8; nt++) {
        int n = nt * 16 + lrow;
#pragma unroll
        for (int reg = 0; reg < 4; reg++) {
            int m = wave * 16 + quad * 4 + reg;
            pt[m * OUTD + n] = acc[nt][reg];
        }
    }
}

// ============ K4: reduce 16 partials + bias + relu ============
__global__ __launch_bounds__(256) void reduce_kernel(const float* __restrict__ partial,
                                                     const float* __restrict__ b_emb,
                                                     float* __restrict__ out) {
    int idx = blockIdx.x * 256 + threadIdx.x;   // 0..32767 (float4 groups of [1024][128])
    const float4* p4 = reinterpret_cast<const float4*>(partial);
    float4 s = p4[idx];
#pragma unroll
    for (int kt = 1; kt < 16; kt++) {
        float4 v = p4[kt * 32768 + idx];
        s.x += v.x; s.y += v.y; s.z += v.z; s.w += v.w;
    }
    float4 bv = reinterpret_cast<const float4*>(b_emb)[idx & 31];
    float4 r;
    r.x = fmaxf(s.x + bv.x, 0.0f);
    r.y = fmaxf(s.y + bv.y, 0.0f);
    r.z = fmaxf(s.z + bv.z, 0.0f);
    r.w = fmaxf(s.w + bv.w, 0.0f);
    reinterpret_cast<float4*>(out)[idx] = r;
}

// ================= Round-1 fallback (f32, fused) for small ws =================
__global__ __launch_bounds__(256) void vals_kernel_f32(const float* __restrict__ hidden,
                                                       const float* __restrict__ W_enc,
                                                       const float* __restrict__ b_enc,
                                                       float* __restrict__ vals) {
    int idx = blockIdx.x * 256 + threadIdx.x;
    int j = idx >> 4, l = idx & 15;
    const float* h = hidden + j * HIDDEN;
    float acc = b_enc[l];
#pragma unroll 8
    for (int k = 0; k < HIDDEN; k++) acc += h[k] * W_enc[k * LATENT + l];
    vals[idx] = acc;
}

__global__ __launch_bounds__(256) void pool_kernel_f32(const float* __restrict__ obs2,
                                                       const float* __restrict__ vals,
                                                       const float* __restrict__ W_emb,
                                                       const float* __restrict__ b_emb,
                                                       float* __restrict__ out) {
    const int i = blockIdx.x;
    const int tid = threadIdx.x;
    __shared__ int owner[NCELLS];
    __shared__ float occ[NCELLS * LATENT];
    __shared__ float partial[OUTD];
    owner[tid] = -1;
    float oix = obs2[i * 2 + 0];
    float oiy = obs2[i * 2 + 1];
    if (isnan(oix) || isnan(oiy)) { oix = 0.0f; oiy = 0.0f; }
    __syncthreads();
    for (int j = tid; j < T_TRACKS; j += 256) {
        if (j == i) continue;
        float ox = obs2[j * 2 + 0], oy = obs2[j * 2 + 1];
        if (isnan(ox) || isnan(oy)) { ox = 0.0f; oy = 0.0f; }
        float gx = (ox - oix) * 0.5f + 8.0f;
        float gy = (oy - oiy) * 0.5f + 8.0f;
        bool inr = (gx >= 0.0f) && (gx < 16.0f) && (gy >= 0.0f) && (gy < 16.0f);
        int c = inr ? ((int)gx * NGRID + (int)gy) : 0;
        atomicMax(&owner[c], j);
    }
    __syncthreads();
    {
        int j = owner[tid];
        bool valid = false;
        if (j >= 0) {
            float ox = obs2[j * 2 + 0], oy = obs2[j * 2 + 1];
            if (isnan(ox) || isnan(oy)) { ox = 0.0f; oy = 0.0f; }
            float gx = (ox - oix) * 0.5f + 8.0f;
            float gy = (oy - oiy) * 0.5f + 8.0f;
            valid = (gx >= 0.0f) && (gx < 16.0f) && (gy >= 0.0f) && (gy < 16.0f);
        }
        const float* vj = vals + (j >= 0 ? j : 0) * LATENT;
#pragma unroll
        for (int l = 0; l < LATENT; l++) occ[tid * LATENT + l] = valid ? vj[l] : 0.0f;
    }
    __syncthreads();
    const int o = tid & (OUTD - 1);
    const int half = tid >> 7;
    const int cbase = half * 128;
    float acc = 0.0f;
    for (int c = cbase; c < cbase + 128; c++) {
#pragma unroll
        for (int l = 0; l < LATENT; l++)
            acc += occ[c * LATENT + l] * W_emb[(l * NCELLS + c) * OUTD + o];
    }
    if (half == 0) partial[o] = acc;
    __syncthreads();
    if (half == 1) out[i * OUTD + o] = fmaxf(acc + partial[o] + b_emb[o], 0.0f);
}

extern "C" void kernel_launch(void* const* d_in, const int* in_sizes, int n_in,
                              void* d_out, int out_size, void* d_ws, size_t ws_size,
                              hipStream_t stream) {
    const float* hidden = (const float*)d_in[0];   // [1024,128]
    const float* obs2   = (const float*)d_in[2];   // [1024,2]
    const float* W_enc  = (const float*)d_in[3];   // [128,16]
    const float* b_enc  = (const float*)d_in[4];   // [16]
    const float* W_emb  = (const float*)d_in[5];   // [4096,128]
    const float* b_emb  = (const float*)d_in[6];   // [128]
    float* out = (float*)d_out;                    // [1024,128]

    if (ws_size < (size_t)WS_NEED) {
        // fallback: round-1 verified f32 path
        float* vals = (float*)d_ws;
        vals_kernel_f32<<<(T_TRACKS * LATENT) / 256, 256, 0, stream>>>(hidden, W_enc, b_enc, vals);
        pool_kernel_f32<<<T_TRACKS, 256, 0, stream>>>(obs2, vals, W_emb, b_emb, out);
        return;
    }

    char* ws = (char*)d_ws;
    ushort_t* vals_bf16 = (ushort_t*)(ws + WS_VALS);
    ushort_t* W_t       = (ushort_t*)(ws + WS_WT);
    ushort_t* occ       = (ushort_t*)(ws + WS_OCC);
    float*    partial   = (float*)(ws + WS_PART);

    prep_kernel<<<320, 256, 0, stream>>>(hidden, W_enc, b_enc, W_emb, vals_bf16, W_t);
    occ_kernel<<<T_TRACKS, 256, 0, stream>>>(obs2, vals_bf16, occ);
    gemm_kernel<<<256, 256, 0, stream>>>(occ, W_t, partial);
    reduce_kernel<<<128, 256, 0, stream>>>(partial, b_emb, out);
}